// Round 9
// baseline (246.476 us; speedup 1.0000x reference)
//
#include <hip/hip_runtime.h>

#define B_ 4
#define C_ 512
#define T_ 2304
#define TP_ 2306
#define KTOT 1536
#define NCLS 200
#define MD 400       // NCLS * OUT_DIM
#define LASTFC 3074

using short8  = __attribute__((ext_vector_type(8))) short;
using f32x4   = __attribute__((ext_vector_type(4))) float;
using us4     = __attribute__((ext_vector_type(4))) unsigned short;
using float4v = __attribute__((ext_vector_type(4))) float;

__device__ __forceinline__ unsigned short f2bf(float f) {
  union { float f; unsigned u; } v; v.f = f;
  unsigned u = v.u;
  u += 0x7fffu + ((u >> 16) & 1u);
  return (unsigned short)(u >> 16);
}

__device__ __forceinline__ void gload16(const void* g, void* l) {
  __builtin_amdgcn_global_load_lds(
      (const __attribute__((address_space(1))) unsigned int*)g,
      (__attribute__((address_space(3))) unsigned int*)l, 16, 0, 0);
}

// ================= prep_all segments (all BW-bound) =================

__device__ void w2t_seg(int bseg, const float* w, unsigned short* WT, float* smem)
{
  float (*tile)[33] = (float(*)[33])smem;
  const int tx = threadIdx.x & 31, ty = threadIdx.x >> 5;
  const int c0 = (bseg % 100)*32, k0 = (bseg / 100)*32;
  #pragma unroll
  for (int i = 0; i < 4; ++i) {
    int k = k0 + ty + i*8, c = c0 + tx;
    tile[ty+i*8][tx] = (c < LASTFC) ? w[(size_t)k*LASTFC + c] : 0.f;
  }
  __syncthreads();
  #pragma unroll
  for (int i = 0; i < 4; ++i) {
    int c = c0 + ty + i*8;
    WT[(size_t)c*512 + k0 + tx] = f2bf(tile[tx][ty+i*8]);
  }
}

__device__ void wcast_seg(int bseg, const float* w0, const float* w1,
                          unsigned short* Wb0, unsigned short* Wb1)
{
  const int total = C_*KTOT;
  for (int idx = bseg*256 + threadIdx.x; idx < total; idx += 512*256) {
    int co = idx / KTOT;
    int rem = idx - co*KTOT;
    int kq = rem >> 9, ci = rem & 511;
    size_t src = (size_t)co*KTOT + ci*3 + kq;
    Wb0[idx] = f2bf(w0[src]);
    Wb1[idx] = f2bf(w1[src]);
  }
}

__device__ void w01t_seg(int bseg, const float* w, unsigned short* WT, float* smem)
{
  float (*tile)[33] = (float(*)[33])smem;
  const int tx = threadIdx.x & 31, ty = threadIdx.x >> 5;
  const int c0 = (bseg & 15)*32, k0 = (bseg >> 4)*32;
  #pragma unroll
  for (int i = 0; i < 4; ++i)
    tile[ty+i*8][tx] = w[(size_t)(k0 + ty + i*8)*512 + c0 + tx];
  __syncthreads();
  #pragma unroll
  for (int i = 0; i < 4; ++i) {
    int c = c0 + ty + i*8;
    WT[(size_t)c*512 + k0 + tx] = f2bf(tile[tx][ty+i*8]);
  }
}

__device__ void qcast_seg(int bseg, const float* qf, unsigned short* qfb)
{
  int idx = bseg*256 + threadIdx.x;
  int r = idx >> 9;
  qfb[idx] = (r < NCLS) ? f2bf(qf[idx]) : 0;
}

__device__ void mask_seg(int bseg, const unsigned char* mraw, float* mf, float* outTail)
{
  int i = bseg*256 + threadIdx.x;
  const bool u8 = (mraw[1] != 0);
  float v = u8 ? (mraw[i] ? 1.f : 0.f) : (((const int*)mraw)[i] ? 1.f : 0.f);
  mf[i] = v;
  outTail[i] = v;
}

__device__ void tcast_seg(int bseg, const float* x, unsigned short* xT,
                          unsigned short* c1T, float* smem)
{
  float (*tile)[33] = (float(*)[33])smem;
  const int tx = threadIdx.x & 31, ty = threadIdx.x >> 5;
  const int t0 = (bseg % 72)*32;
  const int c0 = ((bseg / 72) % 16)*32;
  const int b  = bseg / 1152;
  #pragma unroll
  for (int i = 0; i < 4; ++i) {
    int c = c0 + ty + i*8;
    tile[ty + i*8][tx] = x[((size_t)b*C_ + c)*T_ + t0 + tx];
  }
  __syncthreads();
  #pragma unroll
  for (int i = 0; i < 4; ++i) {
    int t = t0 + ty + i*8;
    xT[((size_t)b*TP_ + 1 + t)*C_ + c0 + tx] = f2bf(tile[tx][ty + i*8]);
  }
  if ((bseg % 72) == 0) {
    int c = c0 + tx;
    if (ty < 4) {
      unsigned short* buf = (ty & 1) ? c1T : xT;
      size_t row = (ty & 2) ? (size_t)(TP_-1) : 0;
      buf[((size_t)b*TP_ + row)*C_ + c] = 0;
    }
  }
}

__global__ __launch_bounds__(256)
void prep_all(const unsigned char* __restrict__ mraw, float* __restrict__ maskF,
              float* __restrict__ outTail,
              const float* __restrict__ hw0, const float* __restrict__ hw1,
              unsigned short* __restrict__ Wb0, unsigned short* __restrict__ Wb1,
              const float* __restrict__ fw2, unsigned short* __restrict__ W2T,
              const float* __restrict__ qf, unsigned short* __restrict__ qfb,
              const float* __restrict__ fw0, unsigned short* __restrict__ fw0T,
              const float* __restrict__ fw1, unsigned short* __restrict__ fw1T,
              const float* __restrict__ fpn, unsigned short* __restrict__ x0T,
              unsigned short* __restrict__ c1T)
{
  __shared__ float smem[1056];
  const int gb = blockIdx.x;
  if (gb < 1600)       w2t_seg(gb, fw2, W2T, smem);
  else if (gb < 2112)  wcast_seg(gb-1600, hw0, hw1, Wb0, Wb1);
  else if (gb < 2368)  w01t_seg(gb-2112, fw0, fw0T, smem);
  else if (gb < 2624)  w01t_seg(gb-2368, fw1, fw1T, smem);
  else if (gb < 3072)  qcast_seg(gb-2624, qf, qfb);
  else if (gb < 3108)  mask_seg(gb-3072, mraw, maskF, outTail);
  else                 tcast_seg(gb-3108, fpn, x0T, c1T, smem);
}

// ================= fused FC0+LN+ReLU -> FC1+LN+ReLU via MFMA (14 blocks x 16 rows) =================
__global__ __launch_bounds__(256)
void fc01_mfma(const unsigned short* __restrict__ qfb,
               const unsigned short* __restrict__ W0T,
               const float* __restrict__ fb0, const float* __restrict__ lg0, const float* __restrict__ lb0,
               const unsigned short* __restrict__ W1T,
               const float* __restrict__ fb1, const float* __restrict__ lg1, const float* __restrict__ lb1,
               unsigned short* __restrict__ Qb)
{
  __shared__ unsigned short Xs[16*16*32];
  __shared__ unsigned short Ws[512*32];
  __shared__ float red[4][2][16];
  const int lane = threadIdx.x & 63;
  const int wave = threadIdx.x >> 6;
  const int row0 = blockIdx.x * 16;
  const int skoff = ((lane&3) ^ ((lane>>3)&3)) * 8;
  const int rsw   = ((lane>>4) ^ ((lane>>1)&3)) * 8;

  #pragma unroll
  for (int i = 0; i < 4; ++i) {
    const int w = i*4 + wave;
    gload16(qfb + (size_t)(row0 + (lane>>2))*512 + w*32 + skoff,
            Xs + w*512 + (lane>>2)*32 + (lane&3)*8);
  }

  #pragma unroll 1
  for (int stage = 0; stage < 2; ++stage) {
    const unsigned short* WT = stage ? W1T : W0T;
    f32x4 acc[8] = {};
    #pragma unroll 1
    for (int w = 0; w < 16; ++w) {
      #pragma unroll
      for (int i = 0; i < 8; ++i) {
        const int r = wave*16 + (lane>>2) + i*64;
        gload16(WT + (size_t)r*512 + w*32 + skoff, Ws + r*32 + (lane&3)*8);
      }
      __syncthreads();
      short8 av = *(const short8*)(Xs + w*512 + (lane&15)*32 + rsw);
      #pragma unroll
      for (int nj = 0; nj < 8; ++nj) {
        short8 bv = *(const short8*)(Ws + (wave*128 + nj*16 + (lane&15))*32 + rsw);
        acc[nj] = __builtin_amdgcn_mfma_f32_16x16x32_bf16(av, bv, acc[nj], 0, 0, 0);
      }
      __syncthreads();
    }

    const float* PB = stage ? fb1 : fb0;
    const float* PG = stage ? lg1 : lg0;
    const float* PE = stage ? lb1 : lb0;
    const int c15 = lane & 15;
    float bb[8], gg[8], ee[8], vv[8][4];
    #pragma unroll
    for (int nj = 0; nj < 8; ++nj) {
      const int c = wave*128 + nj*16 + c15;
      bb[nj] = PB[c]; gg[nj] = PG[c]; ee[nj] = PE[c];
    }
    float s1[4] = {0,0,0,0}, s2[4] = {0,0,0,0};
    #pragma unroll
    for (int nj = 0; nj < 8; ++nj)
      #pragma unroll
      for (int reg = 0; reg < 4; ++reg) {
        float v = acc[nj][reg] + bb[nj];
        vv[nj][reg] = v;
        s1[reg] += v; s2[reg] += v*v;
      }
    #pragma unroll
    for (int off = 1; off < 16; off <<= 1)
      #pragma unroll
      for (int reg = 0; reg < 4; ++reg) {
        s1[reg] += __shfl_xor(s1[reg], off, 64);
        s2[reg] += __shfl_xor(s2[reg], off, 64);
      }
    if (c15 == 0)
      #pragma unroll
      for (int reg = 0; reg < 4; ++reg) {
        int r = (lane>>4)*4 + reg;
        red[wave][0][r] = s1[reg];
        red[wave][1][r] = s2[reg];
      }
    __syncthreads();
    float mu[4], rs[4];
    #pragma unroll
    for (int reg = 0; reg < 4; ++reg) {
      int r = (lane>>4)*4 + reg;
      float t1 = red[0][0][r]+red[1][0][r]+red[2][0][r]+red[3][0][r];
      float t2 = red[0][1][r]+red[1][1][r]+red[2][1][r]+red[3][1][r];
      mu[reg] = t1*(1.f/512.f);
      float var = t2*(1.f/512.f) - mu[reg]*mu[reg];
      rs[reg] = rsqrtf(var + 1e-5f);
    }
    __syncthreads();
    #pragma unroll
    for (int nj = 0; nj < 8; ++nj)
      #pragma unroll
      for (int reg = 0; reg < 4; ++reg) {
        const int r = (lane>>4)*4 + reg;
        const int c = wave*128 + nj*16 + c15;
        float y = fmaxf((vv[nj][reg]-mu[reg])*rs[reg]*gg[nj] + ee[nj], 0.f);
        unsigned short h = f2bf(y);
        if (stage == 0)
          Xs[(c>>5)*512 + r*32 + ((c&31) ^ (((r>>1)&3)<<3))] = h;
        else
          Qb[(size_t)(row0+r)*512 + c] = h;
      }
  }
}

// ================= FC2 as MFMA GEMM (64x64, counted-vmcnt 3-deep, XCD-swizzled) =================
__global__ __launch_bounds__(256)
void fc2_gemm(const unsigned short* __restrict__ A,
              const unsigned short* __restrict__ Qb,
              const float* __restrict__ bias,
              unsigned short* __restrict__ Adyn, float* __restrict__ bdyn)
{
  __shared__ unsigned short As[3*64*32];
  __shared__ unsigned short Bs[3*64*32];
  const int lane = threadIdx.x & 63;
  const int wave = threadIdx.x >> 6;
  const int lid = ((int)blockIdx.x & 7)*25 + ((int)blockIdx.x >> 3);  // 200 blocks
  const int m0 = (lid % 50)*64;
  const int t0 = (lid / 50)*64;
  const int wr = wave >> 1, wc = wave & 1;

  const int srow  = wave*16 + (lane>>2);
  const int skoff = ((lane&3) ^ ((lane>>3)&3)) * 8;
  const int sdst  = (lane&3) * 8;
  const int rsw   = (((lane>>4) ^ ((lane>>1)&3))) * 8;

  f32x4 acc[2][2] = {};
  const int NT = 512/32;   // 16

  auto STAGE = [&](int buf, int tile) {    // 2 loads/thread
    const int kk0 = tile*32;
    gload16(A  + (size_t)(m0 + srow)*512 + kk0 + skoff, As + buf*2048 + srow*32 + sdst);
    gload16(Qb + (size_t)(t0 + srow)*512 + kk0 + skoff, Bs + buf*2048 + srow*32 + sdst);
  };

  STAGE(0, 0); STAGE(1, 1); STAGE(2, 2);
  for (int it = 0; it < NT; ++it) {
    const int cur = it % 3;
    asm volatile("s_waitcnt vmcnt(4)" ::: "memory");
    __builtin_amdgcn_sched_barrier(0);
    asm volatile("s_barrier" ::: "memory");
    short8 av[2], bv[2];
    #pragma unroll
    for (int i = 0; i < 2; ++i)
      av[i] = *(const short8*)(As + cur*2048 + (wr*32 + i*16 + (lane&15))*32 + rsw);
    #pragma unroll
    for (int j = 0; j < 2; ++j)
      bv[j] = *(const short8*)(Bs + cur*2048 + (wc*32 + j*16 + (lane&15))*32 + rsw);
    asm volatile("s_waitcnt lgkmcnt(0)" ::: "memory");
    __builtin_amdgcn_sched_barrier(0);
    asm volatile("s_barrier" ::: "memory");
    const int tl = (it + 3 < NT) ? (it + 3) : (NT - 1);
    STAGE(cur, tl);
    #pragma unroll
    for (int i = 0; i < 2; ++i)
      #pragma unroll
      for (int j = 0; j < 2; ++j)
        acc[i][j] = __builtin_amdgcn_mfma_f32_16x16x32_bf16(av[i], bv[j], acc[i][j], 0, 0, 0);
  }

  #pragma unroll
  for (int i = 0; i < 2; ++i) {
    const int colBase = m0 + wr*32 + i*16 + ((lane>>4)<<2);
    float bb[4];
    #pragma unroll
    for (int r = 0; r < 4; ++r) bb[r] = (colBase + r < LASTFC) ? bias[colBase + r] : 0.f;
    #pragma unroll
    for (int j = 0; j < 2; ++j) {
      const int n = t0 + wc*32 + j*16 + (lane&15);
      if (n >= NCLS) continue;
      #pragma unroll
      for (int r = 0; r < 4; ++r) {
        const int col = colBase + r;
        float v = fmaxf(acc[i][j][r] + bb[r], 0.f);
        if (col < 3072) {
          int ci = col / 6;
          int rem = col - ci*6;
          int o = rem / 3;
          int kq = rem - o*3;
          Adyn[(size_t)(n*2 + o)*KTOT + kq*512 + ci] = f2bf(v);
        } else if (col < LASTFC) {
          bdyn[n*2 + (col - 3072)] = v;
        }
      }
    }
  }
}

// ================= MFMA GEMM, 64x64 tiles, 2x2 waves, counted-vmcnt 3-deep =================
// Grid = GM*36*4 (divisible by 8); m fastest within XCD chunk for L2 reuse.
template<int MODE, int GM>
__global__ __launch_bounds__(256)
void gemm_k(const unsigned short* __restrict__ A,    // (512/448, 1536) bf16 k-contig
            const unsigned short* __restrict__ Xt,   // (B, TP_, 512) bf16 padded
            const float* __restrict__ bias,
            const float* __restrict__ maskF,
            const float* __restrict__ scale,
            unsigned short* __restrict__ outT,       // MODE 0: (B, TP_, 512) bf16
            float* __restrict__ out)                 // MODE 1: (B, 400, T)
{
  __shared__ unsigned short As[3*64*32];   // 12 KB
  __shared__ unsigned short Bs[3*64*32];   // 12 KB
  const int lane = threadIdx.x & 63;
  const int wave = threadIdx.x >> 6;
  const int cpx = (GM*36*4) >> 3;
  const int lid = ((int)blockIdx.x & 7)*cpx + ((int)blockIdx.x >> 3);
  const int m   = lid % GM;
  const int rest = lid / GM;
  const int tt  = rest % 36;
  const int b   = rest / 36;
  const int m0 = m*64, t0 = tt*64;
  const int wr = wave >> 1, wc = wave & 1;

  const int srow  = wave*16 + (lane>>2);
  const int skoff = ((lane&3) ^ ((lane>>3)&3)) * 8;
  const int sdst  = (lane&3) * 8;
  const int rsw   = (((lane>>4) ^ ((lane>>1)&3))) * 8;

  f32x4 acc[2][2] = {};
  const int NT = KTOT/32;   // 48

  auto STAGE = [&](int buf, int tile) {    // 2 loads/thread
    const int kk0  = tile*32;
    const int kidx = kk0 >> 9;             // tap 0..2
    const int ci0  = kk0 & 511;
    gload16(A + (size_t)(m0 + srow)*KTOT + kk0 + skoff, As + buf*2048 + srow*32 + sdst);
    gload16(Xt + ((size_t)b*TP_ + t0 + srow + kidx)*C_ + ci0 + skoff, Bs + buf*2048 + srow*32 + sdst);
  };

  STAGE(0, 0); STAGE(1, 1); STAGE(2, 2);   // 6 in flight
  for (int it = 0; it < NT; ++it) {
    const int cur = it % 3;
    asm volatile("s_waitcnt vmcnt(4)" ::: "memory");   // own tile-it loads done
    __builtin_amdgcn_sched_barrier(0);
    asm volatile("s_barrier" ::: "memory");            // everyone's tile-it loads done
    short8 av[2], bv[2];
    #pragma unroll
    for (int i = 0; i < 2; ++i)
      av[i] = *(const short8*)(As + cur*2048 + (wr*32 + i*16 + (lane&15))*32 + rsw);
    #pragma unroll
    for (int j = 0; j < 2; ++j)
      bv[j] = *(const short8*)(Bs + cur*2048 + (wc*32 + j*16 + (lane&15))*32 + rsw);
    asm volatile("s_waitcnt lgkmcnt(0)" ::: "memory"); // reads retired
    __builtin_amdgcn_sched_barrier(0);
    asm volatile("s_barrier" ::: "memory");            // everyone's reads retired
    const int tl = (it + 3 < NT) ? (it + 3) : (NT - 1);
    STAGE(cur, tl);
    #pragma unroll
    for (int i = 0; i < 2; ++i)
      #pragma unroll
      for (int j = 0; j < 2; ++j)
        acc[i][j] = __builtin_amdgcn_mfma_f32_16x16x32_bf16(av[i], bv[j], acc[i][j], 0, 0, 0);
  }

  if (MODE == 0) {
    #pragma unroll
    for (int i = 0; i < 2; ++i) {
      const int co = m0 + wr*32 + i*16 + ((lane>>4)<<2);
      const float4v bb = *(const float4v*)(bias + co);
      #pragma unroll
      for (int j = 0; j < 2; ++j) {
        const int t = t0 + wc*32 + j*16 + (lane&15);
        const float mf = maskF[b*T_ + t];
        us4 pk;
        #pragma unroll
        for (int r = 0; r < 4; ++r) {
          float v = (acc[i][j][r] + bb[r]) * mf;
          pk[r] = f2bf(fmaxf(v, 0.f));
        }
        *(us4*)(outT + ((size_t)b*TP_ + 1 + t)*C_ + co) = pk;
      }
    }
  } else {
    const float sc = scale[0];
    #pragma unroll
    for (int i = 0; i < 2; ++i) {
      const int mm = m0 + wr*32 + i*16 + ((lane>>4)<<2);
      const float4v bd = *(const float4v*)(bias + mm);
      #pragma unroll
      for (int j = 0; j < 2; ++j) {
        const int t = t0 + wc*32 + j*16 + (lane&15);
        const float mf = maskF[b*T_ + t];
        #pragma unroll
        for (int r = 0; r < 4; ++r) {
          if (mm + r < MD) {
            float v = fmaxf(sc * (acc[i][j][r] + bd[r]) * mf, 0.f);
            out[((size_t)b*MD + mm + r)*T_ + t] = v;
          }
        }
      }
    }
  }
}

extern "C" void kernel_launch(void* const* d_in, const int* in_sizes, int n_in,
                              void* d_out, int out_size, void* d_ws, size_t ws_size,
                              hipStream_t stream)
{
  const float* fpn          = (const float*)d_in[0];
  const unsigned char* mraw = (const unsigned char*)d_in[1];
  const float* qf    = (const float*)d_in[2];
  const float* hw0   = (const float*)d_in[3];
  const float* hb0   = (const float*)d_in[4];
  const float* hw1   = (const float*)d_in[5];
  const float* hb1   = (const float*)d_in[6];
  const float* fw0   = (const float*)d_in[7];
  const float* fb0   = (const float*)d_in[8];
  const float* lg0   = (const float*)d_in[9];
  const float* lb0   = (const float*)d_in[10];
  const float* fw1   = (const float*)d_in[11];
  const float* fb1   = (const float*)d_in[12];
  const float* lg1   = (const float*)d_in[13];
  const float* lb1   = (const float*)d_in[14];
  const float* fw2   = (const float*)d_in[15];
  const float* fb2   = (const float*)d_in[16];
  const float* scale = (const float*)d_in[17];

  char* ws = (char*)d_ws;
  unsigned short* x0T  = (unsigned short*)(ws);                 // 9,445,376
  unsigned short* c2T  = x0T;                                   // alias (x0T dead after conv1)
  unsigned short* c1T  = (unsigned short*)(ws +  9445376);      // 9,445,376
  unsigned short* Wb0  = (unsigned short*)(ws + 18890752);      // 1,572,864
  unsigned short* Wb1  = (unsigned short*)(ws + 20463616);      // 1,572,864
  unsigned short* Adyn = (unsigned short*)(ws + 22036480);      // 1,572,864
  unsigned short* W2T  = (unsigned short*)(ws + 23609344);      // 3,276,800
  unsigned short* Qb   = (unsigned short*)(ws + 26886144);      //   262,144
  unsigned short* qfb  = (unsigned short*)(ws + 27148288);      //   229,376
  unsigned short* fw0T = (unsigned short*)(ws + 27377664);      //   524,288
  unsigned short* fw1T = (unsigned short*)(ws + 27901952);      //   524,288
  float* bdyn  = (float*)(ws + 28426240);                       //     2,048
  float* maskF = (float*)(ws + 28428288);                       //    36,864

  float* out0 = (float*)d_out;
  float* outm = out0 + (size_t)B_*MD*T_;

  prep_all<<<7716, 256, 0, stream>>>(mraw, maskF, outm, hw0, hw1, Wb0, Wb1,
                                     fw2, W2T, qf, qfb, fw0, fw0T, fw1, fw1T,
                                     fpn, x0T, c1T);
  fc01_mfma<<<14, 256, 0, stream>>>(qfb, fw0T, fb0, lg0, lb0, fw1T, fb1, lg1, lb1, Qb);
  fc2_gemm<<<200, 256, 0, stream>>>(W2T, Qb, fb2, Adyn, bdyn);
  gemm_k<0,8><<<1152, 256, 0, stream>>>(Wb0, x0T, hb0, maskF, nullptr, c1T, nullptr);
  gemm_k<0,8><<<1152, 256, 0, stream>>>(Wb1, c1T, hb1, maskF, nullptr, c2T, nullptr);
  gemm_k<1,7><<<1008, 256, 0, stream>>>(Adyn, c2T, bdyn, maskF, scale, nullptr, out0);
}

// Round 10
// 235.428 us; speedup vs baseline: 1.0469x; 1.0469x over previous
//
#include <hip/hip_runtime.h>

#define B_ 4
#define C_ 512
#define T_ 2304
#define TP_ 2306
#define KTOT 1536
#define NCLS 200
#define MD 400       // NCLS * OUT_DIM
#define LASTFC 3074

using short8  = __attribute__((ext_vector_type(8))) short;
using f32x4   = __attribute__((ext_vector_type(4))) float;
using us4     = __attribute__((ext_vector_type(4))) unsigned short;
using float4v = __attribute__((ext_vector_type(4))) float;

__device__ __forceinline__ unsigned short f2bf(float f) {
  union { float f; unsigned u; } v; v.f = f;
  unsigned u = v.u;
  u += 0x7fffu + ((u >> 16) & 1u);
  return (unsigned short)(u >> 16);
}

__device__ __forceinline__ void gload16(const void* g, void* l) {
  __builtin_amdgcn_global_load_lds(
      (const __attribute__((address_space(1))) unsigned int*)g,
      (__attribute__((address_space(3))) unsigned int*)l, 16, 0, 0);
}

// ================= prep_all segments (all BW-bound) =================

__device__ void w2t_seg(int bseg, const float* w, unsigned short* WT, float* smem)
{
  float (*tile)[33] = (float(*)[33])smem;
  const int tx = threadIdx.x & 31, ty = threadIdx.x >> 5;
  const int c0 = (bseg % 100)*32, k0 = (bseg / 100)*32;
  #pragma unroll
  for (int i = 0; i < 4; ++i) {
    int k = k0 + ty + i*8, c = c0 + tx;
    tile[ty+i*8][tx] = (c < LASTFC) ? w[(size_t)k*LASTFC + c] : 0.f;
  }
  __syncthreads();
  #pragma unroll
  for (int i = 0; i < 4; ++i) {
    int c = c0 + ty + i*8;
    WT[(size_t)c*512 + k0 + tx] = f2bf(tile[tx][ty+i*8]);
  }
}

__device__ void wcast_seg(int bseg, const float* w0, const float* w1,
                          unsigned short* Wb0, unsigned short* Wb1)
{
  const int total = C_*KTOT;
  for (int idx = bseg*256 + threadIdx.x; idx < total; idx += 512*256) {
    int co = idx / KTOT;
    int rem = idx - co*KTOT;
    int kq = rem >> 9, ci = rem & 511;
    size_t src = (size_t)co*KTOT + ci*3 + kq;
    Wb0[idx] = f2bf(w0[src]);
    Wb1[idx] = f2bf(w1[src]);
  }
}

__device__ void w01t_seg(int bseg, const float* w, unsigned short* WT, float* smem)
{
  float (*tile)[33] = (float(*)[33])smem;
  const int tx = threadIdx.x & 31, ty = threadIdx.x >> 5;
  const int c0 = (bseg & 15)*32, k0 = (bseg >> 4)*32;
  #pragma unroll
  for (int i = 0; i < 4; ++i)
    tile[ty+i*8][tx] = w[(size_t)(k0 + ty + i*8)*512 + c0 + tx];
  __syncthreads();
  #pragma unroll
  for (int i = 0; i < 4; ++i) {
    int c = c0 + ty + i*8;
    WT[(size_t)c*512 + k0 + tx] = f2bf(tile[tx][ty+i*8]);
  }
}

__device__ void qcast_seg(int bseg, const float* qf, unsigned short* qfb)
{
  int idx = bseg*256 + threadIdx.x;
  int r = idx >> 9;
  qfb[idx] = (r < NCLS) ? f2bf(qf[idx]) : 0;
}

__device__ void mask_seg(int bseg, const unsigned char* mraw, float* mf, float* outTail)
{
  int i = bseg*256 + threadIdx.x;
  const bool u8 = (mraw[1] != 0);
  float v = u8 ? (mraw[i] ? 1.f : 0.f) : (((const int*)mraw)[i] ? 1.f : 0.f);
  mf[i] = v;
  outTail[i] = v;
}

__device__ void tcast_seg(int bseg, const float* x, unsigned short* xT,
                          unsigned short* c1T, float* smem)
{
  float (*tile)[33] = (float(*)[33])smem;
  const int tx = threadIdx.x & 31, ty = threadIdx.x >> 5;
  const int t0 = (bseg % 72)*32;
  const int c0 = ((bseg / 72) % 16)*32;
  const int b  = bseg / 1152;
  #pragma unroll
  for (int i = 0; i < 4; ++i) {
    int c = c0 + ty + i*8;
    tile[ty + i*8][tx] = x[((size_t)b*C_ + c)*T_ + t0 + tx];
  }
  __syncthreads();
  #pragma unroll
  for (int i = 0; i < 4; ++i) {
    int t = t0 + ty + i*8;
    xT[((size_t)b*TP_ + 1 + t)*C_ + c0 + tx] = f2bf(tile[tx][ty + i*8]);
  }
  if ((bseg % 72) == 0) {
    int c = c0 + tx;
    if (ty < 4) {
      unsigned short* buf = (ty & 1) ? c1T : xT;
      size_t row = (ty & 2) ? (size_t)(TP_-1) : 0;
      buf[((size_t)b*TP_ + row)*C_ + c] = 0;
    }
  }
}

__global__ __launch_bounds__(256)
void prep_all(const unsigned char* __restrict__ mraw, float* __restrict__ maskF,
              float* __restrict__ outTail,
              const float* __restrict__ hw0, const float* __restrict__ hw1,
              unsigned short* __restrict__ Wb0, unsigned short* __restrict__ Wb1,
              const float* __restrict__ fw2, unsigned short* __restrict__ W2T,
              const float* __restrict__ qf, unsigned short* __restrict__ qfb,
              const float* __restrict__ fw0, unsigned short* __restrict__ fw0T,
              const float* __restrict__ fw1, unsigned short* __restrict__ fw1T,
              const float* __restrict__ fpn, unsigned short* __restrict__ x0T,
              unsigned short* __restrict__ c1T)
{
  __shared__ float smem[1056];
  const int gb = blockIdx.x;
  if (gb < 1600)       w2t_seg(gb, fw2, W2T, smem);
  else if (gb < 2112)  wcast_seg(gb-1600, hw0, hw1, Wb0, Wb1);
  else if (gb < 2368)  w01t_seg(gb-2112, fw0, fw0T, smem);
  else if (gb < 2624)  w01t_seg(gb-2368, fw1, fw1T, smem);
  else if (gb < 3072)  qcast_seg(gb-2624, qf, qfb);
  else if (gb < 3108)  mask_seg(gb-3072, mraw, maskF, outTail);
  else                 tcast_seg(gb-3108, fpn, x0T, c1T, smem);
}

// ================= fused FC0+LN+ReLU -> FC1+LN+ReLU via MFMA (14 blocks x 16 rows) =================
__global__ __launch_bounds__(256)
void fc01_mfma(const unsigned short* __restrict__ qfb,
               const unsigned short* __restrict__ W0T,
               const float* __restrict__ fb0, const float* __restrict__ lg0, const float* __restrict__ lb0,
               const unsigned short* __restrict__ W1T,
               const float* __restrict__ fb1, const float* __restrict__ lg1, const float* __restrict__ lb1,
               unsigned short* __restrict__ Qb)
{
  __shared__ unsigned short Xs[16*16*32];
  __shared__ unsigned short Ws[512*32];
  __shared__ float red[4][2][16];
  const int lane = threadIdx.x & 63;
  const int wave = threadIdx.x >> 6;
  const int row0 = blockIdx.x * 16;
  const int skoff = ((lane&3) ^ ((lane>>3)&3)) * 8;
  const int rsw   = ((lane>>4) ^ ((lane>>1)&3)) * 8;

  #pragma unroll
  for (int i = 0; i < 4; ++i) {
    const int w = i*4 + wave;
    gload16(qfb + (size_t)(row0 + (lane>>2))*512 + w*32 + skoff,
            Xs + w*512 + (lane>>2)*32 + (lane&3)*8);
  }

  #pragma unroll 1
  for (int stage = 0; stage < 2; ++stage) {
    const unsigned short* WT = stage ? W1T : W0T;
    f32x4 acc[8] = {};
    #pragma unroll 1
    for (int w = 0; w < 16; ++w) {
      #pragma unroll
      for (int i = 0; i < 8; ++i) {
        const int r = wave*16 + (lane>>2) + i*64;
        gload16(WT + (size_t)r*512 + w*32 + skoff, Ws + r*32 + (lane&3)*8);
      }
      __syncthreads();
      short8 av = *(const short8*)(Xs + w*512 + (lane&15)*32 + rsw);
      #pragma unroll
      for (int nj = 0; nj < 8; ++nj) {
        short8 bv = *(const short8*)(Ws + (wave*128 + nj*16 + (lane&15))*32 + rsw);
        acc[nj] = __builtin_amdgcn_mfma_f32_16x16x32_bf16(av, bv, acc[nj], 0, 0, 0);
      }
      __syncthreads();
    }

    const float* PB = stage ? fb1 : fb0;
    const float* PG = stage ? lg1 : lg0;
    const float* PE = stage ? lb1 : lb0;
    const int c15 = lane & 15;
    float bb[8], gg[8], ee[8], vv[8][4];
    #pragma unroll
    for (int nj = 0; nj < 8; ++nj) {
      const int c = wave*128 + nj*16 + c15;
      bb[nj] = PB[c]; gg[nj] = PG[c]; ee[nj] = PE[c];
    }
    float s1[4] = {0,0,0,0}, s2[4] = {0,0,0,0};
    #pragma unroll
    for (int nj = 0; nj < 8; ++nj)
      #pragma unroll
      for (int reg = 0; reg < 4; ++reg) {
        float v = acc[nj][reg] + bb[nj];
        vv[nj][reg] = v;
        s1[reg] += v; s2[reg] += v*v;
      }
    #pragma unroll
    for (int off = 1; off < 16; off <<= 1)
      #pragma unroll
      for (int reg = 0; reg < 4; ++reg) {
        s1[reg] += __shfl_xor(s1[reg], off, 64);
        s2[reg] += __shfl_xor(s2[reg], off, 64);
      }
    if (c15 == 0)
      #pragma unroll
      for (int reg = 0; reg < 4; ++reg) {
        int r = (lane>>4)*4 + reg;
        red[wave][0][r] = s1[reg];
        red[wave][1][r] = s2[reg];
      }
    __syncthreads();
    float mu[4], rs[4];
    #pragma unroll
    for (int reg = 0; reg < 4; ++reg) {
      int r = (lane>>4)*4 + reg;
      float t1 = red[0][0][r]+red[1][0][r]+red[2][0][r]+red[3][0][r];
      float t2 = red[0][1][r]+red[1][1][r]+red[2][1][r]+red[3][1][r];
      mu[reg] = t1*(1.f/512.f);
      float var = t2*(1.f/512.f) - mu[reg]*mu[reg];
      rs[reg] = rsqrtf(var + 1e-5f);
    }
    __syncthreads();
    #pragma unroll
    for (int nj = 0; nj < 8; ++nj)
      #pragma unroll
      for (int reg = 0; reg < 4; ++reg) {
        const int r = (lane>>4)*4 + reg;
        const int c = wave*128 + nj*16 + c15;
        float y = fmaxf((vv[nj][reg]-mu[reg])*rs[reg]*gg[nj] + ee[nj], 0.f);
        unsigned short h = f2bf(y);
        if (stage == 0)
          Xs[(c>>5)*512 + r*32 + ((c&31) ^ (((r>>1)&3)<<3))] = h;
        else
          Qb[(size_t)(row0+r)*512 + c] = h;
      }
  }
}

// ================= FC2 as MFMA GEMM (64x64, counted-vmcnt 3-deep, XCD-swizzled) =================
__global__ __launch_bounds__(256)
void fc2_gemm(const unsigned short* __restrict__ A,
              const unsigned short* __restrict__ Qb,
              const float* __restrict__ bias,
              unsigned short* __restrict__ Adyn, float* __restrict__ bdyn)
{
  __shared__ unsigned short As[3*64*32];
  __shared__ unsigned short Bs[3*64*32];
  const int lane = threadIdx.x & 63;
  const int wave = threadIdx.x >> 6;
  const int lid = ((int)blockIdx.x & 7)*25 + ((int)blockIdx.x >> 3);  // 200 blocks
  const int m0 = (lid % 50)*64;
  const int t0 = (lid / 50)*64;
  const int wr = wave >> 1, wc = wave & 1;

  const int srow  = wave*16 + (lane>>2);
  const int skoff = ((lane&3) ^ ((lane>>3)&3)) * 8;
  const int sdst  = (lane&3) * 8;
  const int rsw   = (((lane>>4) ^ ((lane>>1)&3))) * 8;

  f32x4 acc[2][2] = {};
  const int NT = 512/32;   // 16

  auto STAGE = [&](int buf, int tile) {    // 2 loads/thread
    const int kk0 = tile*32;
    gload16(A  + (size_t)(m0 + srow)*512 + kk0 + skoff, As + buf*2048 + srow*32 + sdst);
    gload16(Qb + (size_t)(t0 + srow)*512 + kk0 + skoff, Bs + buf*2048 + srow*32 + sdst);
  };

  STAGE(0, 0); STAGE(1, 1); STAGE(2, 2);
  for (int it = 0; it < NT; ++it) {
    const int cur = it % 3;
    asm volatile("s_waitcnt vmcnt(4)" ::: "memory");
    __builtin_amdgcn_sched_barrier(0);
    asm volatile("s_barrier" ::: "memory");
    short8 av[2], bv[2];
    #pragma unroll
    for (int i = 0; i < 2; ++i)
      av[i] = *(const short8*)(As + cur*2048 + (wr*32 + i*16 + (lane&15))*32 + rsw);
    #pragma unroll
    for (int j = 0; j < 2; ++j)
      bv[j] = *(const short8*)(Bs + cur*2048 + (wc*32 + j*16 + (lane&15))*32 + rsw);
    asm volatile("s_waitcnt lgkmcnt(0)" ::: "memory");
    __builtin_amdgcn_sched_barrier(0);
    asm volatile("s_barrier" ::: "memory");
    const int tl = (it + 3 < NT) ? (it + 3) : (NT - 1);
    STAGE(cur, tl);
    #pragma unroll
    for (int i = 0; i < 2; ++i)
      #pragma unroll
      for (int j = 0; j < 2; ++j)
        acc[i][j] = __builtin_amdgcn_mfma_f32_16x16x32_bf16(av[i], bv[j], acc[i][j], 0, 0, 0);
  }

  #pragma unroll
  for (int i = 0; i < 2; ++i) {
    const int colBase = m0 + wr*32 + i*16 + ((lane>>4)<<2);
    float bb[4];
    #pragma unroll
    for (int r = 0; r < 4; ++r) bb[r] = (colBase + r < LASTFC) ? bias[colBase + r] : 0.f;
    #pragma unroll
    for (int j = 0; j < 2; ++j) {
      const int n = t0 + wc*32 + j*16 + (lane&15);
      if (n >= NCLS) continue;
      #pragma unroll
      for (int r = 0; r < 4; ++r) {
        const int col = colBase + r;
        float v = fmaxf(acc[i][j][r] + bb[r], 0.f);
        if (col < 3072) {
          int ci = col / 6;
          int rem = col - ci*6;
          int o = rem / 3;
          int kq = rem - o*3;
          Adyn[(size_t)(n*2 + o)*KTOT + kq*512 + ci] = f2bf(v);
        } else if (col < LASTFC) {
          bdyn[n*2 + (col - 3072)] = v;
        }
      }
    }
  }
}

// ================= MFMA GEMM, 64(M)x128(N), BK=64, 3-buf single-barrier pipeline =================
// One barrier/iter: staging into buf[(it+2)%3] is safe because every wave passing
// barrier(it) already executed lgkmcnt(0) of iter it-1 (reads of that buffer retired),
// and vmcnt(6) BEFORE the barrier guarantees all waves' tile-it loads are in LDS.
// LDS rows are 64 bf16 (8 octets of 16B); swizzle: LDS[r][o] = G[r][o ^ (r&7)].
template<int MODE, int GM>
__global__ __launch_bounds__(256)
void gemm_k(const unsigned short* __restrict__ A,    // (512/448, 1536) bf16 k-contig
            const unsigned short* __restrict__ Xt,   // (B, TP_, 512) bf16 padded
            const float* __restrict__ bias,
            const float* __restrict__ maskF,
            const float* __restrict__ scale,
            unsigned short* __restrict__ outT,       // MODE 0: (B, TP_, 512) bf16
            float* __restrict__ out)                 // MODE 1: (B, 400, T)
{
  __shared__ unsigned short As[3*64*64];   // 24 KB
  __shared__ unsigned short Bs[3*128*64];  // 48 KB
  const int lane = threadIdx.x & 63;
  const int wave = threadIdx.x >> 6;
  const int cpx = (GM*18*4) >> 3;
  const int lid = ((int)blockIdx.x & 7)*cpx + ((int)blockIdx.x >> 3);
  const int m   = lid % GM;
  const int rest = lid / GM;
  const int tt  = rest % 18;
  const int b   = rest / 18;
  const int m0 = m*64, t0 = tt*128;
  const int wr = wave >> 1, wc = wave & 1;   // wave tile: 32(M) x 64(N)

  const int s8off = ((lane&7) ^ ((lane>>3)&7)) * 8;  // staging src octet (elements)
  const int rq    = lane & 7;                        // fragment row & 7

  f32x4 acc[2][4] = {};
  const int NT = KTOT/64;   // 24

  auto STAGE = [&](int buf, int tile) {    // 6 loads/thread
    const int kk0  = tile*64;
    const int kidx = kk0 >> 9;             // tap 0..2 (512%64==0: uniform per tile)
    const int ci0  = kk0 & 511;
    #pragma unroll
    for (int i = 0; i < 2; ++i) {
      const int r = i*32 + wave*8 + (lane>>3);
      gload16(A + (size_t)(m0 + r)*KTOT + kk0 + s8off, As + buf*4096 + r*64 + (lane&7)*8);
    }
    #pragma unroll
    for (int i = 0; i < 4; ++i) {
      const int r = i*32 + wave*8 + (lane>>3);
      gload16(Xt + ((size_t)b*TP_ + t0 + r + kidx)*C_ + ci0 + s8off, Bs + buf*8192 + r*64 + (lane&7)*8);
    }
  };

  STAGE(0, 0); STAGE(1, 1);                // depth-2 prefetch, 12 loads in flight
  for (int it = 0; it < NT; ++it) {
    const int cur = it % 3;
    asm volatile("s_waitcnt vmcnt(6)" ::: "memory");   // all waves' tile-it loads done...
    __builtin_amdgcn_sched_barrier(0);
    asm volatile("s_barrier" ::: "memory");            // ...after this barrier
    short8 av[2][2], bv[2][4];
    #pragma unroll
    for (int ks = 0; ks < 2; ++ks) {
      #pragma unroll
      for (int i = 0; i < 2; ++i) {
        const int r = wr*32 + i*16 + (lane&15);
        const int oct = (ks*4 + (lane>>4)) ^ rq;
        av[ks][i] = *(const short8*)(As + cur*4096 + r*64 + oct*8);
      }
      #pragma unroll
      for (int j = 0; j < 4; ++j) {
        const int r = wc*64 + j*16 + (lane&15);
        const int oct = (ks*4 + (lane>>4)) ^ rq;
        bv[ks][j] = *(const short8*)(Bs + cur*8192 + r*64 + oct*8);
      }
    }
    const int tl = (it + 2 < NT) ? (it + 2) : (NT - 1);  // uniform 6 loads/iter
    STAGE((it + 2) % 3, tl);                             // overwrites buf[(it-1)%3]: safe
    asm volatile("s_waitcnt lgkmcnt(0)" ::: "memory");   // my frag reads retired
    __builtin_amdgcn_sched_barrier(0);
    #pragma unroll
    for (int ks = 0; ks < 2; ++ks)
      #pragma unroll
      for (int i = 0; i < 2; ++i)
        #pragma unroll
        for (int j = 0; j < 4; ++j)
          acc[i][j] = __builtin_amdgcn_mfma_f32_16x16x32_bf16(av[ks][i], bv[ks][j], acc[i][j], 0, 0, 0);
  }

  if (MODE == 0) {
    #pragma unroll
    for (int i = 0; i < 2; ++i) {
      const int co = m0 + wr*32 + i*16 + ((lane>>4)<<2);
      const float4v bb = *(const float4v*)(bias + co);
      #pragma unroll
      for (int j = 0; j < 4; ++j) {
        const int t = t0 + wc*64 + j*16 + (lane&15);
        const float mf = maskF[b*T_ + t];
        us4 pk;
        #pragma unroll
        for (int r = 0; r < 4; ++r) {
          float v = (acc[i][j][r] + bb[r]) * mf;
          pk[r] = f2bf(fmaxf(v, 0.f));
        }
        *(us4*)(outT + ((size_t)b*TP_ + 1 + t)*C_ + co) = pk;
      }
    }
  } else {
    const float sc = scale[0];
    #pragma unroll
    for (int i = 0; i < 2; ++i) {
      const int mm = m0 + wr*32 + i*16 + ((lane>>4)<<2);
      const float4v bd = *(const float4v*)(bias + mm);
      #pragma unroll
      for (int j = 0; j < 4; ++j) {
        const int t = t0 + wc*64 + j*16 + (lane&15);
        const float mf = maskF[b*T_ + t];
        #pragma unroll
        for (int r = 0; r < 4; ++r) {
          if (mm + r < MD) {
            float v = fmaxf(sc * (acc[i][j][r] + bd[r]) * mf, 0.f);
            out[((size_t)b*MD + mm + r)*T_ + t] = v;
          }
        }
      }
    }
  }
}

extern "C" void kernel_launch(void* const* d_in, const int* in_sizes, int n_in,
                              void* d_out, int out_size, void* d_ws, size_t ws_size,
                              hipStream_t stream)
{
  const float* fpn          = (const float*)d_in[0];
  const unsigned char* mraw = (const unsigned char*)d_in[1];
  const float* qf    = (const float*)d_in[2];
  const float* hw0   = (const float*)d_in[3];
  const float* hb0   = (const float*)d_in[4];
  const float* hw1   = (const float*)d_in[5];
  const float* hb1   = (const float*)d_in[6];
  const float* fw0   = (const float*)d_in[7];
  const float* fb0   = (const float*)d_in[8];
  const float* lg0   = (const float*)d_in[9];
  const float* lb0   = (const float*)d_in[10];
  const float* fw1   = (const float*)d_in[11];
  const float* fb1   = (const float*)d_in[12];
  const float* lg1   = (const float*)d_in[13];
  const float* lb1   = (const float*)d_in[14];
  const float* fw2   = (const float*)d_in[15];
  const float* fb2   = (const float*)d_in[16];
  const float* scale = (const float*)d_in[17];

  char* ws = (char*)d_ws;
  unsigned short* x0T  = (unsigned short*)(ws);                 // 9,445,376
  unsigned short* c2T  = x0T;                                   // alias (x0T dead after conv1)
  unsigned short* c1T  = (unsigned short*)(ws +  9445376);      // 9,445,376
  unsigned short* Wb0  = (unsigned short*)(ws + 18890752);      // 1,572,864
  unsigned short* Wb1  = (unsigned short*)(ws + 20463616);      // 1,572,864
  unsigned short* Adyn = (unsigned short*)(ws + 22036480);      // 1,572,864
  unsigned short* W2T  = (unsigned short*)(ws + 23609344);      // 3,276,800
  unsigned short* Qb   = (unsigned short*)(ws + 26886144);      //   262,144
  unsigned short* qfb  = (unsigned short*)(ws + 27148288);      //   229,376
  unsigned short* fw0T = (unsigned short*)(ws + 27377664);      //   524,288
  unsigned short* fw1T = (unsigned short*)(ws + 27901952);      //   524,288
  float* bdyn  = (float*)(ws + 28426240);                       //     2,048
  float* maskF = (float*)(ws + 28428288);                       //    36,864

  float* out0 = (float*)d_out;
  float* outm = out0 + (size_t)B_*MD*T_;

  prep_all<<<7716, 256, 0, stream>>>(mraw, maskF, outm, hw0, hw1, Wb0, Wb1,
                                     fw2, W2T, qf, qfb, fw0, fw0T, fw1, fw1T,
                                     fpn, x0T, c1T);
  fc01_mfma<<<14, 256, 0, stream>>>(qfb, fw0T, fb0, lg0, lb0, fw1T, fb1, lg1, lb1, Qb);
  fc2_gemm<<<200, 256, 0, stream>>>(W2T, Qb, fb2, Adyn, bdyn);
  gemm_k<0,8><<<576, 256, 0, stream>>>(Wb0, x0T, hb0, maskF, nullptr, c1T, nullptr);
  gemm_k<0,8><<<576, 256, 0, stream>>>(Wb1, c1T, hb1, maskF, nullptr, c2T, nullptr);
  gemm_k<1,7><<<504, 256, 0, stream>>>(Adyn, c2T, bdyn, maskF, scale, nullptr, out0);
}